// Round 3
// baseline (528.299 us; speedup 1.0000x reference)
//
#include <hip/hip_runtime.h>
#include <hip/hip_bf16.h>

#define NC      80
#define BATCH   1048576
#define CHUNKS  (BATCH / 32)           // 32768 K-chunks of 32 rows
#define NTHR    256
#define NBLK    1024
#define NWAVES  (NBLK * NTHR / 64)     // 4096 waves
#define CPW     (CHUNKS / NWAVES)      // exactly 8 contiguous chunks per wave
#define LDSW    17                     // dword stride per class row (odd -> bank spread)
#define WAVE_LDS (NC * LDSW)           // 1360 dwords per wave
#define NTILE   15                     // upper-triangle 16x16 tiles of 80x80

using bf16x8 = __attribute__((ext_vector_type(8))) __bf16;
using f32x4  = __attribute__((ext_vector_type(4))) float;

// Stage 1: G = label^T @ label (upper-triangle 16x16 tiles), bf16 MFMA.
// Labels in {0,1} -> bf16 truncation exact; partial sums are integers < 2^24
// -> fp32 accumulation (incl. atomicAdd) exact and order-independent.
//
// v3: depth-2 register prefetch (next chunk's 10 dwordx4 in flight while the
// current chunk runs pack->LDS->frag->MFMA), contiguous 80 KB stream per wave,
// direct atomicAdd epilogue (no intermediate reduce kernel).
__global__ __launch_bounds__(NTHR) void gram_kernel(const float* __restrict__ label,
                                                    float* __restrict__ G) {
    __shared__ unsigned int Lt[4 * WAVE_LDS];   // 21760 B wave-private staging
    __shared__ float Gs[NC * NC];               // 25600 B block accumulator

    const int tid  = threadIdx.x;
    const int lane = tid & 63;
    const int wv   = tid >> 6;
    const int m    = lane & 15;   // class-within-tile (frag row)
    const int quad = lane >> 4;   // k-subchunk selector
    unsigned int* lt = Lt + wv * WAVE_LDS;

    for (int u = tid; u < NC * NC; u += NTHR) Gs[u] = 0.0f;
    __syncthreads();   // Gs zeros visible before any epilogue atomics

    // loop-invariant per-lane load/store decomposition
    int rp_[5], c4_[5];
#pragma unroll
    for (int i = 0; i < 5; ++i) {
        int p  = i * 64 + lane;    // float4-pair unit index, 0..319
        rp_[i] = p / 20;           // row-pair 0..15
        c4_[i] = p % 20;           // float4-within-row 0..19
    }

    const int wid = blockIdx.x * 4 + wv;
    const float* span = label + (size_t)wid * CPW * (32 * NC);

    f32x4 acc[NTILE];
#pragma unroll
    for (int t = 0; t < NTILE; ++t) acc[t] = (f32x4){0.f, 0.f, 0.f, 0.f};

    // issue one chunk's 10 coalesced dwordx4 loads (rows 2rp & 2rp+1)
    auto LOAD = [&](float4* A, float4* B, int c) {
        const float* cb = span + (size_t)c * (32 * NC);
#pragma unroll
        for (int i = 0; i < 5; ++i) {
            const float* pa = cb + (2 * rp_[i]) * NC + 4 * c4_[i];
            A[i] = *(const float4*)pa;         // row 2rp   (k even)
            B[i] = *(const float4*)(pa + NC);  // row 2rp+1 (k odd)
        }
    };

    // pack to bf16 k-pairs -> wave-private transposed LDS -> frags -> 15 MFMAs
    auto PROC = [&](const float4* A, const float4* B) {
#pragma unroll
        for (int i = 0; i < 5; ++i) {
            unsigned int p0 = (__float_as_uint(B[i].x) & 0xFFFF0000u) | (__float_as_uint(A[i].x) >> 16);
            unsigned int p1 = (__float_as_uint(B[i].y) & 0xFFFF0000u) | (__float_as_uint(A[i].y) >> 16);
            unsigned int p2 = (__float_as_uint(B[i].z) & 0xFFFF0000u) | (__float_as_uint(A[i].z) >> 16);
            unsigned int p3 = (__float_as_uint(B[i].w) & 0xFFFF0000u) | (__float_as_uint(A[i].w) >> 16);
            unsigned int base = (unsigned)(4 * c4_[i]) * LDSW + rp_[i];
            lt[base]            = p0;
            lt[base + LDSW]     = p1;
            lt[base + 2 * LDSW] = p2;
            lt[base + 3 * LDSW] = p3;
        }
        bf16x8 frag[5];
#pragma unroll
        for (int t = 0; t < 5; ++t) {
            // class = 16t+m, k-pairs quad*4..quad*4+3; bank = (17m+4q)&31 -> 2-way max
            const unsigned int* fp = lt + (unsigned)(16 * t + m) * LDSW + quad * 4;
            union { unsigned int u[4]; bf16x8 b; } cv;
            cv.u[0] = fp[0]; cv.u[1] = fp[1]; cv.u[2] = fp[2]; cv.u[3] = fp[3];
            frag[t] = cv.b;
        }
        int idx = 0;
#pragma unroll
        for (int ti = 0; ti < 5; ++ti)
#pragma unroll
            for (int tj = ti; tj < 5; ++tj) {
                acc[idx] = __builtin_amdgcn_mfma_f32_16x16x32_bf16(
                    frag[ti], frag[tj], acc[idx], 0, 0, 0);
                ++idx;
            }
    };

    float4 A0[5], B0[5], A1[5], B1[5];
    LOAD(A0, B0, 0);
    LOAD(A1, B1, 1);
#pragma unroll
    for (int i = 0; i < 3; ++i) {
        PROC(A0, B0); LOAD(A0, B0, 2 * i + 2);
        PROC(A1, B1); LOAD(A1, B1, 2 * i + 3);
    }
    PROC(A0, B0);
    PROC(A1, B1);

    // wave accs -> Gs (C/D layout: col = lane&15, row = quad*4 + reg)
    {
        int idx = 0;
#pragma unroll
        for (int ti = 0; ti < 5; ++ti)
#pragma unroll
            for (int tj = ti; tj < 5; ++tj) {
#pragma unroll
                for (int r = 0; r < 4; ++r) {
                    atomicAdd(&Gs[(16 * ti + quad * 4 + r) * NC + 16 * tj + m],
                              acc[idx][r]);
                }
                ++idx;
            }
    }
    __syncthreads();

    // block partial -> global G (upper-triangle tiles; 15 atomics/thread,
    // depth-1024 same-address chains pipelined across 3840 addresses)
    {
        const int r  = tid >> 4;
        const int cl = tid & 15;
#pragma unroll
        for (int ti = 0; ti < 5; ++ti)
#pragma unroll
            for (int tj = ti; tj < 5; ++tj) {
                int row = 16 * ti + r, col = 16 * tj + cl;
                atomicAdd(&G[row * NC + col], Gs[row * NC + col]);
            }
    }
}

// Stage 2: target = cooc/(count+eps) + eye ; smooth-L1-ish ; mean -> out[0]
__global__ __launch_bounds__(256) void loss_kernel(const float* __restrict__ pre_adj,
                                                   const float* __restrict__ G,
                                                   float* __restrict__ out) {
    const int tid = threadIdx.x;
    float sum = 0.f;
    for (int u = tid; u < NC * NC; u += 256) {
        int i = u / NC, j = u - i * NC;
        float target;
        if (i == j) {
            target = 1.0f;
        } else {
            // G stored only for tile(i) <= tile(j); G is symmetric
            float num = ((i >> 4) <= (j >> 4)) ? G[i * NC + j] : G[j * NC + i];
            float cnt = G[i * NC + i];   // count[i] = diag (binary labels)
            target = num / (cnt + 1e-7f);
        }
        float r = fabsf(pre_adj[u] - target);
        sum += (r < 1.0f) ? r * r : (r - 0.5f);
    }
#pragma unroll
    for (int off = 32; off > 0; off >>= 1) sum += __shfl_down(sum, off);
    __shared__ float ws[4];
    if ((tid & 63) == 0) ws[tid >> 6] = sum;
    __syncthreads();
    if (tid == 0) out[0] = (ws[0] + ws[1] + ws[2] + ws[3]) * (1.0f / 6400.0f);
}

extern "C" void kernel_launch(void* const* d_in, const int* in_sizes, int n_in,
                              void* d_out, int out_size, void* d_ws, size_t ws_size,
                              hipStream_t stream) {
    const float* pre_adj = (const float*)d_in[0];   // [80,80]
    const float* label   = (const float*)d_in[1];   // [1048576,80]
    float* out = (float*)d_out;                     // scalar
    float* G   = (float*)d_ws;                      // 6400 f32 accumulator

    hipMemsetAsync(G, 0, NC * NC * sizeof(float), stream);
    gram_kernel<<<NBLK, NTHR, 0, stream>>>(label, G);
    loss_kernel<<<1, 256, 0, stream>>>(pre_adj, G, out);
}